// Round 12
// baseline (541.361 us; speedup 1.0000x reference)
//
#include <hip/hip_runtime.h>
#include <hip/hip_bf16.h>

#define HD 128
#define LN_EPS 1e-5f

typedef __attribute__((ext_vector_type(8))) short short8;
typedef __attribute__((ext_vector_type(4))) float f32x4;

__device__ __forceinline__ unsigned short f2bf(float f) {
    union { float f; unsigned u; } v; v.f = f;
    unsigned r = (v.u + 0x7fffu + ((v.u >> 16) & 1u)) >> 16;
    return (unsigned short)r;
}

__device__ __forceinline__ unsigned cvtpk(float lo, float hi) {
    unsigned r;
    asm("v_cvt_pk_bf16_f32 %0, %1, %2" : "=v"(r) : "v"(lo), "v"(hi));
    return r;
}
__device__ __forceinline__ unsigned cvtpk_abs(float lo, float hi) {
    unsigned r;
    asm("v_cvt_pk_bf16_f32 %0, abs(%1), abs(%2)" : "=v"(r) : "v"(lo), "v"(hi));
    return r;
}
// packed |a-b| on bf16 pairs -> packed bf16
__device__ __forceinline__ unsigned absd_bf2(unsigned a, unsigned b) {
    float alo = __uint_as_float(a << 16), ahi = __uint_as_float(a & 0xffff0000u);
    float blo = __uint_as_float(b << 16), bhi = __uint_as_float(b & 0xffff0000u);
    return cvtpk_abs(alo - blo, ahi - bhi);
}

__device__ __forceinline__ float wave_sum_all(float v) {
    #pragma unroll
    for (int o = 32; o > 0; o >>= 1) v += __shfl_xor(v, o);
    return v;
}

// ---------------- W1 (L x 384x128 f32) -> bf16 fragment-major, all layers
__global__ __launch_bounds__(256) void w1bf_kernel(
    const float* __restrict__ W1, unsigned short* __restrict__ out, int total)
{
    int idx = blockIdx.x * 256 + threadIdx.x;
    if (idx >= total) return;
    int lw  = idx / 49152;
    int rem = idx - lw * 49152;
    int j  = rem & 7;
    int c  = (rem >> 3) & 15;
    int ks = (rem >> 7) & 3;
    int ct = (rem >> 9) & 7;
    int q  = rem >> 12;
    out[idx] = f2bf(W1[(size_t)lw * 49152 + (size_t)(q * 32 + ks * 8 + j) * 128 + ct * 16 + c]);
}

// ---------------- copy W_upd[l][0:128] into wcomb[l][0:128]
__global__ __launch_bounds__(256) void copy_upd_kernel(
    const float* __restrict__ W_upd, float* __restrict__ wcomb, int total)
{
    int idx = blockIdx.x * 256 + threadIdx.x;
    if (idx >= total) return;
    int l = idx / 16384, r = idx - l * 16384;
    wcomb[(size_t)l * 32768 + r] = W_upd[(size_t)l * 32768 + r];
}

// ---------------- fp32 GEMM: out[N][128] = cat(in0,in1)[N][K] @ W[K][128] (+bias)(+res)
// optional fused LN+relu epilogue (g != nullptr); optional bf16 mirror store (out_bf).
__global__ __launch_bounds__(256) void gemm_rows_kernel(
    const float* __restrict__ in0, int s0, const float* __restrict__ in1, int s1,
    const float* __restrict__ W, const float* __restrict__ bias,
    const float* __restrict__ res, const float* __restrict__ g,
    const float* __restrict__ bln, float* __restrict__ out,
    unsigned* __restrict__ out_bf, int N)
{
    __shared__ __align__(16) float rows[4][8][256];
    int tid = threadIdx.x, wv = tid >> 6, lane = tid & 63;
    int rbase = (blockIdx.x * 4 + wv) * 8;
    if (rbase >= N) return;
    int K = in1 ? 256 : 128;
    int r = lane >> 3, seg = lane & 7;
    int row = min(rbase + r, N - 1);
    {
        const float4* p = (const float4*)(in0 + (size_t)row * s0 + seg * 16);
        float4* q = (float4*)&rows[wv][r][seg * 16];
        #pragma unroll
        for (int i = 0; i < 4; i++) q[i] = p[i];
        if (in1) {
            const float4* p1 = (const float4*)(in1 + (size_t)row * s1 + seg * 16);
            float4* q1 = (float4*)&rows[wv][r][128 + seg * 16];
            #pragma unroll
            for (int i = 0; i < 4; i++) q1[i] = p1[i];
        }
    }
    asm volatile("s_waitcnt lgkmcnt(0)" ::: "memory");
    float2 acc[8];
    float2 bv = make_float2(0.f, 0.f);
    if (bias) bv = *(const float2*)(bias + 2 * lane);
    #pragma unroll
    for (int t = 0; t < 8; t++) acc[t] = bv;
    for (int k = 0; k < K; k += 4) {
        float2 w0 = *(const float2*)(W + (size_t)(k + 0) * 128 + 2 * lane);
        float2 w1 = *(const float2*)(W + (size_t)(k + 1) * 128 + 2 * lane);
        float2 w2 = *(const float2*)(W + (size_t)(k + 2) * 128 + 2 * lane);
        float2 w3 = *(const float2*)(W + (size_t)(k + 3) * 128 + 2 * lane);
        #pragma unroll
        for (int t = 0; t < 8; t++) {
            float4 a = *(const float4*)&rows[wv][t][k];
            acc[t].x = fmaf(a.x, w0.x, acc[t].x); acc[t].y = fmaf(a.x, w0.y, acc[t].y);
            acc[t].x = fmaf(a.y, w1.x, acc[t].x); acc[t].y = fmaf(a.y, w1.y, acc[t].y);
            acc[t].x = fmaf(a.z, w2.x, acc[t].x); acc[t].y = fmaf(a.z, w2.y, acc[t].y);
            acc[t].x = fmaf(a.w, w3.x, acc[t].x); acc[t].y = fmaf(a.w, w3.y, acc[t].y);
        }
    }
    if (res) {
        #pragma unroll
        for (int t = 0; t < 8; t++) {
            int rw = rbase + t;
            if (rw < N) {
                float2 rv = *(const float2*)(res + (size_t)rw * 128 + 2 * lane);
                acc[t].x += rv.x; acc[t].y += rv.y;
            }
        }
    }
    if (g) {
        float2 gv = *(const float2*)(g + 2 * lane);
        float2 lv = *(const float2*)(bln + 2 * lane);
        #pragma unroll
        for (int t = 0; t < 8; t++) {
            int rw = rbase + t;
            if (rw >= N) break;
            float s  = wave_sum_all(acc[t].x + acc[t].y);
            float s2 = wave_sum_all(acc[t].x * acc[t].x + acc[t].y * acc[t].y);
            float mu = s * (1.f / 128.f);
            float var = s2 * (1.f / 128.f) - mu * mu;
            float rs = rsqrtf(var + LN_EPS);
            float2 y;
            y.x = fmaxf((acc[t].x - mu) * rs * gv.x + lv.x, 0.f);
            y.y = fmaxf((acc[t].y - mu) * rs * gv.y + lv.y, 0.f);
            *(float2*)(out + (size_t)rw * 128 + 2 * lane) = y;
            if (out_bf) out_bf[(size_t)rw * 64 + lane] = cvtpk(y.x, y.y);
        }
    } else {
        #pragma unroll
        for (int t = 0; t < 8; t++) {
            int rw = rbase + t;
            if (rw < N) *(float2*)(out + (size_t)rw * 128 + 2 * lane) = acc[t];
        }
    }
}

// ---------------- CSR build ----------------
__global__ __launch_bounds__(256) void hist_kernel(
    const int* __restrict__ dstA, int* __restrict__ cnt, int E, int Etot)
{
    for (int e = blockIdx.x * 256 + threadIdx.x; e < Etot; e += gridDim.x * 256) {
        int di = (e < E) ? dstA[e] : (e - E);
        atomicAdd(&cnt[di], 1);
    }
}

__global__ __launch_bounds__(256) void scan_kernel(
    const int* __restrict__ cnt, int* __restrict__ rowptr, int* __restrict__ cursor,
    int N, int Etot)
{
    __shared__ int ls[256];
    int t = threadIdx.x;
    int chunk = (N + 255) / 256;
    int lo = t * chunk, hi = min(lo + chunk, N);
    int s = 0;
    for (int i = lo; i < hi; i++) s += cnt[i];
    ls[t] = s;
    __syncthreads();
    for (int off = 1; off < 256; off <<= 1) {
        int v = (t >= off) ? ls[t - off] : 0;
        __syncthreads();
        ls[t] += v;
        __syncthreads();
    }
    int run = ls[t] - s;
    for (int i = lo; i < hi; i++) {
        rowptr[i] = run; cursor[i] = run;
        run += cnt[i];
    }
    if (t == 0) rowptr[N] = Etot;
}

__global__ __launch_bounds__(256) void scatter_kernel(
    const int* __restrict__ srcA, const int* __restrict__ dstA,
    int* __restrict__ cursor, int* __restrict__ esrc, int* __restrict__ edst,
    int E, int Etot)
{
    for (int e = blockIdx.x * 256 + threadIdx.x; e < Etot; e += gridDim.x * 256) {
        int si = (e < E) ? srcA[e] : (e - E);
        int di = (e < E) ? dstA[e] : (e - E);
        int pos = atomicAdd(&cursor[di], 1);
        esrc[pos] = si;
        edst[pos] = di;
    }
}

// ---------------- edge scores via MFMA (CSR order), bf16 h source
// T14 async-stage: tile t+1's row loads are issued right after the staging
// barrier and held in registers through tile t's MFMA; written to LDS next iter.
// planes: xi +0, xj +16384, d +32768 (plane = 64 rows x 256 B, XOR swizzle)
__global__ __launch_bounds__(256, 3) void edge_mfma_kernel(
    const unsigned* __restrict__ hbf,
    const int* __restrict__ esrc, const int* __restrict__ edst,
    const unsigned short* __restrict__ w1bf, const float* __restrict__ b1,
    const float* __restrict__ W2, const float* __restrict__ b2p,
    float* __restrict__ score, int Etot)
{
    __shared__ __align__(16) short sim[3][64][128];   // 48 KB
    __shared__ float pl[4][64];
    int tid = threadIdx.x, wv = tid >> 6, lane = tid & 63;
    char* simb = (char*)sim;

    short8 wf[12][2];
    {
        int ks = lane >> 4, c = lane & 15;
        #pragma unroll
        for (int q = 0; q < 12; q++)
            #pragma unroll
            for (int n = 0; n < 2; n++) {
                int ct = wv * 2 + n;
                wf[q][n] = *(const short8*)(w1bf + (size_t)(((q * 8 + ct) * 4 + ks) * 128 + c * 8));
            }
    }
    float b1x = b1[wv * 32 + (lane & 15)],  b1y = b1[wv * 32 + 16 + (lane & 15)];
    float w2x = W2[wv * 32 + (lane & 15)],  w2y = W2[wv * 32 + 16 + (lane & 15)];
    float b2 = b2p[0];

    int nb = gridDim.x;
    int swz = (blockIdx.x & 7) * (nb >> 3) + (blockIdx.x >> 3);
    int ntiles = (Etot + 63) >> 6;
    int t0 = (int)(((long long)ntiles * swz) / nb);
    int t1 = (int)(((long long)ntiles * (swz + 1)) / nb);
    if (t0 >= t1) return;

    int el = tid >> 2, seg = tid & 3;

    // ---- prologue: load tile t0's rows; prefetch tile t0+1's indices
    int ecur = min((t0 << 6) + el, Etot - 1);
    int si = esrc[ecur], di = edst[ecur];
    const uint4* xi0 = (const uint4*)(hbf + (size_t)di * 64 + seg * 16);
    const uint4* xj0 = (const uint4*)(hbf + (size_t)si * 64 + seg * 16);
    uint4 a0 = xi0[0], a1 = xi0[1], a2 = xi0[2], a3 = xi0[3];
    uint4 b0 = xj0[0], b1q = xj0[1], b2q = xj0[2], b3q = xj0[3];
    {
        int tn = (t0 + 1 < t1) ? (t0 + 1) : t0;
        int en = min((tn << 6) + el, Etot - 1);
        si = esrc[en]; di = edst[en];   // si/di now hold NEXT tile's indices
    }

    for (int tile = t0; tile < t1; tile++) {
        // ---- write current tile (registers) to LDS
        {
            int rowoff = el * 256, sw = (el & 7) << 4;
            uint4 d0, d1, d2, d3;
            d0.x = absd_bf2(a0.x, b0.x);  d0.y = absd_bf2(a0.y, b0.y);
            d0.z = absd_bf2(a0.z, b0.z);  d0.w = absd_bf2(a0.w, b0.w);
            d1.x = absd_bf2(a1.x, b1q.x); d1.y = absd_bf2(a1.y, b1q.y);
            d1.z = absd_bf2(a1.z, b1q.z); d1.w = absd_bf2(a1.w, b1q.w);
            d2.x = absd_bf2(a2.x, b2q.x); d2.y = absd_bf2(a2.y, b2q.y);
            d2.z = absd_bf2(a2.z, b2q.z); d2.w = absd_bf2(a2.w, b2q.w);
            d3.x = absd_bf2(a3.x, b3q.x); d3.y = absd_bf2(a3.y, b3q.y);
            d3.z = absd_bf2(a3.z, b3q.z); d3.w = absd_bf2(a3.w, b3q.w);
            int o0 = rowoff + ((seg * 64 +  0) ^ sw);
            int o1 = rowoff + ((seg * 64 + 16) ^ sw);
            int o2 = rowoff + ((seg * 64 + 32) ^ sw);
            int o3 = rowoff + ((seg * 64 + 48) ^ sw);
            *(uint4*)(simb + o0)         = a0;  *(uint4*)(simb + o1)         = a1;
            *(uint4*)(simb + o2)         = a2;  *(uint4*)(simb + o3)         = a3;
            *(uint4*)(simb + 16384 + o0) = b0;  *(uint4*)(simb + 16384 + o1) = b1q;
            *(uint4*)(simb + 16384 + o2) = b2q; *(uint4*)(simb + 16384 + o3) = b3q;
            *(uint4*)(simb + 32768 + o0) = d0;  *(uint4*)(simb + 32768 + o1) = d1;
            *(uint4*)(simb + 32768 + o2) = d2;  *(uint4*)(simb + 32768 + o3) = d3;
        }
        __syncthreads();
        // ---- issue NEXT tile's loads now; they complete under the MFMA below
        uint4 na0, na1, na2, na3, nb0, nb1, nb2, nb3;
        {
            const uint4* nxi = (const uint4*)(hbf + (size_t)di * 64 + seg * 16);
            const uint4* nxj = (const uint4*)(hbf + (size_t)si * 64 + seg * 16);
            na0 = nxi[0]; na1 = nxi[1]; na2 = nxi[2]; na3 = nxi[3];
            nb0 = nxj[0]; nb1 = nxj[1]; nb2 = nxj[2]; nb3 = nxj[3];
        }
        // prefetch indices for tile+2
        {
            int tn = (tile + 2 < t1) ? (tile + 2) : (t1 - 1);
            int en = min((tn << 6) + el, Etot - 1);
            si = esrc[en]; di = edst[en];
        }
        // ---- MFMA on current tile
        f32x4 acc[4][2];
        #pragma unroll
        for (int m = 0; m < 4; m++)
            #pragma unroll
            for (int n = 0; n < 2; n++)
                #pragma unroll
                for (int r = 0; r < 4; r++) acc[m][n][r] = 0.f;
        __builtin_amdgcn_s_setprio(1);
        #pragma unroll
        for (int q = 0; q < 12; q++) {
            int third = q >> 2;
            int kin = ((q & 3) * 64 + (lane >> 4) * 16);
            short8 af[4];
            #pragma unroll
            for (int m = 0; m < 4; m++) {
                int elr = m * 16 + (lane & 15);
                int addr = third * 16384 + elr * 256 + (kin ^ ((elr & 7) << 4));
                af[m] = *(const short8*)(simb + addr);
            }
            #pragma unroll
            for (int m = 0; m < 4; m++)
                #pragma unroll
                for (int n = 0; n < 2; n++)
                    acc[m][n] = __builtin_amdgcn_mfma_f32_16x16x32_bf16(af[m], wf[q][n], acc[m][n], 0, 0, 0);
        }
        __builtin_amdgcn_s_setprio(0);
        #pragma unroll
        for (int m = 0; m < 4; m++) {
            #pragma unroll
            for (int r = 0; r < 4; r++) {
                float v = fmaxf(acc[m][0][r] + b1x, 0.f) * w2x
                        + fmaxf(acc[m][1][r] + b1y, 0.f) * w2y;
                v += __shfl_xor(v, 1); v += __shfl_xor(v, 2);
                v += __shfl_xor(v, 4); v += __shfl_xor(v, 8);
                if ((lane & 15) == 0) pl[wv][m * 16 + (lane >> 4) * 4 + r] = v;
            }
        }
        __syncthreads();
        // ---- scores: each wave writes its own 16 edges
        {
            int ebase = tile << 6;
            if (lane < 16) {
                int idx = wv * 16 + lane;
                int e = ebase + idx;
                if (e < Etot) {
                    float z = pl[0][idx] + pl[1][idx] + pl[2][idx] + pl[3][idx] + b2;
                    score[e] = 1.f / (1.f + __expf(-z));
                }
            }
        }
        // ---- rotate prefetched registers into current
        a0 = na0; a1 = na1; a2 = na2; a3 = na3;
        b0 = nb0; b1q = nb1; b2q = nb2; b3q = nb3;
    }
}

// ---------------- pre_agg[n] = sum score[pos]*hbf[esrc[pos]]  (fp32 accum)
__global__ __launch_bounds__(256) void gather_kernel(
    const int* __restrict__ rowptr, const int* __restrict__ esrc,
    const float* __restrict__ score, const unsigned* __restrict__ hbf,
    float* __restrict__ pre_agg, int N)
{
    int nb = gridDim.x;
    int bid = blockIdx.x;
    int swz = (bid & 7) * (nb >> 3) + (bid >> 3);
    int wvi = threadIdx.x >> 6, lane = threadIdx.x & 63;
    int node = swz * 4 + wvi;
    if (node >= N) return;
    int p0 = rowptr[node], p1 = rowptr[node + 1];
    float2 a0 = make_float2(0.f, 0.f), a1 = a0, a2 = a0, a3 = a0;
    for (int base = p0; base < p1; base += 64) {
        int cnt = min(64, p1 - base);
        int sidx = 0; float sc = 0.f;
        if (lane < cnt) {
            sidx = esrc[base + lane];
            sc = score[base + lane];
        }
        int i = 0;
        for (; i + 4 <= cnt; i += 4) {
            float s0 = __shfl(sc, i),     s1 = __shfl(sc, i + 1);
            float s2 = __shfl(sc, i + 2), s3 = __shfl(sc, i + 3);
            int r0 = __shfl(sidx, i),     r1 = __shfl(sidx, i + 1);
            int r2 = __shfl(sidx, i + 2), r3 = __shfl(sidx, i + 3);
            unsigned u0 = hbf[(size_t)r0 * 64 + lane];
            unsigned u1 = hbf[(size_t)r1 * 64 + lane];
            unsigned u2 = hbf[(size_t)r2 * 64 + lane];
            unsigned u3 = hbf[(size_t)r3 * 64 + lane];
            a0.x = fmaf(s0, __uint_as_float(u0 << 16), a0.x);
            a0.y = fmaf(s0, __uint_as_float(u0 & 0xffff0000u), a0.y);
            a1.x = fmaf(s1, __uint_as_float(u1 << 16), a1.x);
            a1.y = fmaf(s1, __uint_as_float(u1 & 0xffff0000u), a1.y);
            a2.x = fmaf(s2, __uint_as_float(u2 << 16), a2.x);
            a2.y = fmaf(s2, __uint_as_float(u2 & 0xffff0000u), a2.y);
            a3.x = fmaf(s3, __uint_as_float(u3 << 16), a3.x);
            a3.y = fmaf(s3, __uint_as_float(u3 & 0xffff0000u), a3.y);
        }
        for (; i < cnt; i++) {
            float s = __shfl(sc, i);
            int rr = __shfl(sidx, i);
            unsigned u = hbf[(size_t)rr * 64 + lane];
            a0.x = fmaf(s, __uint_as_float(u << 16), a0.x);
            a0.y = fmaf(s, __uint_as_float(u & 0xffff0000u), a0.y);
        }
    }
    float2 o;
    o.x = (a0.x + a1.x) + (a2.x + a3.x);
    o.y = (a0.y + a1.y) + (a2.y + a3.y);
    *(float2*)(pre_agg + (size_t)node * 128 + 2 * lane) = o;
}

// ---------------- classifier
__global__ __launch_bounds__(256) void cls_kernel(
    const float* __restrict__ hin, const float* __restrict__ W1,
    const float* __restrict__ b1, const float* __restrict__ W2,
    const float* __restrict__ b2, float* __restrict__ out, int N)
{
    __shared__ __align__(16) float w1[HD * 64];
    __shared__ __align__(16) float w2[64 * 40];
    __shared__ __align__(16) float hs[4][HD];
    __shared__ float ts[4][64];
    for (int i = threadIdx.x; i < HD * 64; i += 256) w1[i] = W1[i];
    for (int i = threadIdx.x; i < 64 * 40; i += 256) w2[i] = W2[i];
    int sub = threadIdx.x >> 6, t = threadIdx.x & 63;
    float b1j = b1[t];
    float b2j = (t < 40) ? b2[t] : 0.f;
    __syncthreads();
    for (int base = blockIdx.x * 4; base < N; base += gridDim.x * 4) {
        int i = base + sub; bool val = i < N;
        if (val) { hs[sub][t] = hin[(size_t)i * HD + t]; hs[sub][64 + t] = hin[(size_t)i * HD + 64 + t]; }
        __syncthreads();
        float acc = b1j;
        const float* hr = hs[sub];
        #pragma unroll 8
        for (int k = 0; k < HD; k += 4) {
            float4 hv = *(const float4*)(hr + k);
            acc = fmaf(hv.x, w1[(k + 0) * 64 + t], acc);
            acc = fmaf(hv.y, w1[(k + 1) * 64 + t], acc);
            acc = fmaf(hv.z, w1[(k + 2) * 64 + t], acc);
            acc = fmaf(hv.w, w1[(k + 3) * 64 + t], acc);
        }
        ts[sub][t] = fmaxf(acc, 0.f);
        __syncthreads();
        if (val && t < 40) {
            float o = b2j;
            const float* tr = ts[sub];
            #pragma unroll 8
            for (int k = 0; k < 64; k++) o = fmaf(tr[k], w2[k * 40 + t], o);
            out[(size_t)i * 40 + t] = o;
        }
        __syncthreads();
    }
}

extern "C" void kernel_launch(void* const* d_in, const int* in_sizes, int n_in,
                              void* d_out, int out_size, void* d_ws, size_t ws_size,
                              hipStream_t stream)
{
    const float* x      = (const float*)d_in[0];
    const int*   ei     = (const int*)d_in[1];
    const float* proj_W = (const float*)d_in[2];
    const float* proj_b = (const float*)d_in[3];
    const float* ln0_g  = (const float*)d_in[4];
    const float* ln0_b  = (const float*)d_in[5];
    const float* sim_W1 = (const float*)d_in[6];
    const float* sim_b1 = (const float*)d_in[7];
    const float* sim_W2 = (const float*)d_in[8];
    const float* sim_b2 = (const float*)d_in[9];
    const float* W_msg  = (const float*)d_in[10];
    const float* W_upd  = (const float*)d_in[11];
    const float* b_upd  = (const float*)d_in[12];
    const float* ln_g   = (const float*)d_in[13];
    const float* ln_b   = (const float*)d_in[14];
    const float* cls_W1 = (const float*)d_in[15];
    const float* cls_b1 = (const float*)d_in[16];
    const float* cls_W2 = (const float*)d_in[17];
    const float* cls_b2 = (const float*)d_in[18];

    int N = in_sizes[0] / 256;
    int E = in_sizes[1] / 2;
    int L = in_sizes[6] / (3 * HD * HD);
    int Etot = E + N;
    const int* srcA = ei;
    const int* dstA = ei + E;

    float* ws = (float*)d_ws;
    size_t nh = (size_t)N * HD;
    float* h       = ws;
    float* pre_agg = h + nh;
    float* score   = pre_agg + nh;
    float* wcomb   = score + Etot + 64;                      // L * 256*128 floats
    unsigned* hbf  = (unsigned*)(wcomb + (size_t)L * 32768); // N*64 uints
    unsigned short* w1bf = (unsigned short*)(hbf + nh / 2);
    int*   cnt    = (int*)(w1bf + (size_t)L * 49152);
    int*   rowptr = cnt + N;
    int*   cursor = rowptr + N + 1;
    int*   esrc   = cursor + N;
    int*   edst   = esrc + Etot;

    int gemm_blocks = (N + 31) / 32;

    // CSR build (edge_index constant across layers)
    hipMemsetAsync(cnt, 0, (size_t)N * sizeof(int), stream);
    hist_kernel<<<512, 256, 0, stream>>>(dstA, cnt, E, Etot);
    scan_kernel<<<1, 256, 0, stream>>>(cnt, rowptr, cursor, N, Etot);
    scatter_kernel<<<512, 256, 0, stream>>>(srcA, dstA, cursor, esrc, edst, E, Etot);

    // W1 -> bf16 fragment-major (all layers, once)
    int w1_total = L * 49152;
    w1bf_kernel<<<(w1_total + 255) / 256, 256, 0, stream>>>(sim_W1, w1bf, w1_total);

    // wcomb[l] = [ W_upd[l][0:128] ; W_msg[l] @ W_upd[l][128:256] ]
    int cp_total = L * 16384;
    copy_upd_kernel<<<(cp_total + 255) / 256, 256, 0, stream>>>(W_upd, wcomb, cp_total);
    for (int l = 0; l < L; l++) {
        gemm_rows_kernel<<<(128 + 31) / 32, 256, 0, stream>>>(
            W_msg + (size_t)l * 16384, 128, nullptr, 0,
            W_upd + (size_t)l * 32768 + 16384, nullptr, nullptr, nullptr, nullptr,
            wcomb + (size_t)l * 32768 + 16384, nullptr, 128);
    }

    // h = relu(LN(x @ proj_W + b)), hbf mirror
    gemm_rows_kernel<<<gemm_blocks, 256, 0, stream>>>(x, 256, x + 128, 256, proj_W, proj_b,
                                                      nullptr, ln0_g, ln0_b, h, hbf, N);

    int gather_blocks = (N + 3) / 4;          // 5000, divisible by 8
    for (int l = 0; l < L; l++) {
        edge_mfma_kernel<<<768, 256, 0, stream>>>(hbf, esrc, edst,
                                                  w1bf + (size_t)l * 49152, sim_b1 + l * HD,
                                                  sim_W2 + l * HD, sim_b2 + l, score, Etot);
        gather_kernel<<<gather_blocks, 256, 0, stream>>>(rowptr, esrc, score, hbf, pre_agg, N);
        gemm_rows_kernel<<<gemm_blocks, 256, 0, stream>>>(h, 128, pre_agg, 128,
                                                          wcomb + (size_t)l * 32768,
                                                          b_upd + l * HD, h,
                                                          ln_g + l * HD, ln_b + l * HD, h, hbf, N);
    }
    cls_kernel<<<768, 256, 0, stream>>>(h, cls_W1, cls_b1, cls_W2, cls_b2, (float*)d_out, N);
}

// Round 13
// 454.731 us; speedup vs baseline: 1.1905x; 1.1905x over previous
//
#include <hip/hip_runtime.h>
#include <hip/hip_bf16.h>

#define HD 128
#define LN_EPS 1e-5f

typedef __attribute__((ext_vector_type(8))) short short8;
typedef __attribute__((ext_vector_type(4))) float f32x4;

__device__ __forceinline__ unsigned short f2bf(float f) {
    union { float f; unsigned u; } v; v.f = f;
    unsigned r = (v.u + 0x7fffu + ((v.u >> 16) & 1u)) >> 16;
    return (unsigned short)r;
}

__device__ __forceinline__ unsigned cvtpk(float lo, float hi) {
    unsigned r;
    asm("v_cvt_pk_bf16_f32 %0, %1, %2" : "=v"(r) : "v"(lo), "v"(hi));
    return r;
}
__device__ __forceinline__ unsigned cvtpk_abs(float lo, float hi) {
    unsigned r;
    asm("v_cvt_pk_bf16_f32 %0, abs(%1), abs(%2)" : "=v"(r) : "v"(lo), "v"(hi));
    return r;
}
// packed |a-b| on bf16 pairs -> packed bf16
__device__ __forceinline__ unsigned absd_bf2(unsigned a, unsigned b) {
    float alo = __uint_as_float(a << 16), ahi = __uint_as_float(a & 0xffff0000u);
    float blo = __uint_as_float(b << 16), bhi = __uint_as_float(b & 0xffff0000u);
    return cvtpk_abs(alo - blo, ahi - bhi);
}

__device__ __forceinline__ float wave_sum_all(float v) {
    #pragma unroll
    for (int o = 32; o > 0; o >>= 1) v += __shfl_xor(v, o);
    return v;
}

// ---------------- W1 (L x 384x128 f32) -> bf16 fragment-major, all layers
__global__ __launch_bounds__(256) void w1bf_kernel(
    const float* __restrict__ W1, unsigned short* __restrict__ out, int total)
{
    int idx = blockIdx.x * 256 + threadIdx.x;
    if (idx >= total) return;
    int lw  = idx / 49152;
    int rem = idx - lw * 49152;
    int j  = rem & 7;
    int c  = (rem >> 3) & 15;
    int ks = (rem >> 7) & 3;
    int ct = (rem >> 9) & 7;
    int q  = rem >> 12;
    out[idx] = f2bf(W1[(size_t)lw * 49152 + (size_t)(q * 32 + ks * 8 + j) * 128 + ct * 16 + c]);
}

// ---------------- wcomb (L x 256x128 f32) -> bf16 fragment-major
__global__ __launch_bounds__(256) void wcbf_kernel(
    const float* __restrict__ wcomb, unsigned short* __restrict__ out, int total)
{
    int idx = blockIdx.x * 256 + threadIdx.x;
    if (idx >= total) return;
    int lw  = idx >> 15;            // / 32768
    int rem = idx & 32767;
    int j  = rem & 7;
    int c  = (rem >> 3) & 15;
    int ks = (rem >> 7) & 3;
    int ct = (rem >> 9) & 7;
    int q  = rem >> 12;             // 0..7
    out[idx] = f2bf(wcomb[(size_t)lw * 32768 + (size_t)(q * 32 + ks * 8 + j) * 128 + ct * 16 + c]);
}

// ---------------- copy W_upd[l][0:128] into wcomb[l][0:128]
__global__ __launch_bounds__(256) void copy_upd_kernel(
    const float* __restrict__ W_upd, float* __restrict__ wcomb, int total)
{
    int idx = blockIdx.x * 256 + threadIdx.x;
    if (idx >= total) return;
    int l = idx / 16384, r = idx - l * 16384;
    wcomb[(size_t)l * 32768 + r] = W_upd[(size_t)l * 32768 + r];
}

// ---------------- fp32 GEMM: out[N][128] = cat(in0,in1)[N][K] @ W[K][128] (+bias)(+res)
// optional fused LN+relu epilogue (g != nullptr); optional bf16 mirror store (out_bf).
__global__ __launch_bounds__(256) void gemm_rows_kernel(
    const float* __restrict__ in0, int s0, const float* __restrict__ in1, int s1,
    const float* __restrict__ W, const float* __restrict__ bias,
    const float* __restrict__ res, const float* __restrict__ g,
    const float* __restrict__ bln, float* __restrict__ out,
    unsigned* __restrict__ out_bf, int N)
{
    __shared__ __align__(16) float rows[4][8][256];
    int tid = threadIdx.x, wv = tid >> 6, lane = tid & 63;
    int rbase = (blockIdx.x * 4 + wv) * 8;
    if (rbase >= N) return;
    int K = in1 ? 256 : 128;
    int r = lane >> 3, seg = lane & 7;
    int row = min(rbase + r, N - 1);
    {
        const float4* p = (const float4*)(in0 + (size_t)row * s0 + seg * 16);
        float4* q = (float4*)&rows[wv][r][seg * 16];
        #pragma unroll
        for (int i = 0; i < 4; i++) q[i] = p[i];
        if (in1) {
            const float4* p1 = (const float4*)(in1 + (size_t)row * s1 + seg * 16);
            float4* q1 = (float4*)&rows[wv][r][128 + seg * 16];
            #pragma unroll
            for (int i = 0; i < 4; i++) q1[i] = p1[i];
        }
    }
    asm volatile("s_waitcnt lgkmcnt(0)" ::: "memory");
    float2 acc[8];
    float2 bv = make_float2(0.f, 0.f);
    if (bias) bv = *(const float2*)(bias + 2 * lane);
    #pragma unroll
    for (int t = 0; t < 8; t++) acc[t] = bv;
    for (int k = 0; k < K; k += 4) {
        float2 w0 = *(const float2*)(W + (size_t)(k + 0) * 128 + 2 * lane);
        float2 w1 = *(const float2*)(W + (size_t)(k + 1) * 128 + 2 * lane);
        float2 w2 = *(const float2*)(W + (size_t)(k + 2) * 128 + 2 * lane);
        float2 w3 = *(const float2*)(W + (size_t)(k + 3) * 128 + 2 * lane);
        #pragma unroll
        for (int t = 0; t < 8; t++) {
            float4 a = *(const float4*)&rows[wv][t][k];
            acc[t].x = fmaf(a.x, w0.x, acc[t].x); acc[t].y = fmaf(a.x, w0.y, acc[t].y);
            acc[t].x = fmaf(a.y, w1.x, acc[t].x); acc[t].y = fmaf(a.y, w1.y, acc[t].y);
            acc[t].x = fmaf(a.z, w2.x, acc[t].x); acc[t].y = fmaf(a.z, w2.y, acc[t].y);
            acc[t].x = fmaf(a.w, w3.x, acc[t].x); acc[t].y = fmaf(a.w, w3.y, acc[t].y);
        }
    }
    if (res) {
        #pragma unroll
        for (int t = 0; t < 8; t++) {
            int rw = rbase + t;
            if (rw < N) {
                float2 rv = *(const float2*)(res + (size_t)rw * 128 + 2 * lane);
                acc[t].x += rv.x; acc[t].y += rv.y;
            }
        }
    }
    if (g) {
        float2 gv = *(const float2*)(g + 2 * lane);
        float2 lv = *(const float2*)(bln + 2 * lane);
        #pragma unroll
        for (int t = 0; t < 8; t++) {
            int rw = rbase + t;
            if (rw >= N) break;
            float s  = wave_sum_all(acc[t].x + acc[t].y);
            float s2 = wave_sum_all(acc[t].x * acc[t].x + acc[t].y * acc[t].y);
            float mu = s * (1.f / 128.f);
            float var = s2 * (1.f / 128.f) - mu * mu;
            float rs = rsqrtf(var + LN_EPS);
            float2 y;
            y.x = fmaxf((acc[t].x - mu) * rs * gv.x + lv.x, 0.f);
            y.y = fmaxf((acc[t].y - mu) * rs * gv.y + lv.y, 0.f);
            *(float2*)(out + (size_t)rw * 128 + 2 * lane) = y;
            if (out_bf) out_bf[(size_t)rw * 64 + lane] = cvtpk(y.x, y.y);
        }
    } else {
        #pragma unroll
        for (int t = 0; t < 8; t++) {
            int rw = rbase + t;
            if (rw < N) *(float2*)(out + (size_t)rw * 128 + 2 * lane) = acc[t];
        }
    }
}

// ---------------- CSR build ----------------
__global__ __launch_bounds__(256) void hist_kernel(
    const int* __restrict__ dstA, int* __restrict__ cnt, int E, int Etot)
{
    for (int e = blockIdx.x * 256 + threadIdx.x; e < Etot; e += gridDim.x * 256) {
        int di = (e < E) ? dstA[e] : (e - E);
        atomicAdd(&cnt[di], 1);
    }
}

__global__ __launch_bounds__(256) void scan_kernel(
    const int* __restrict__ cnt, int* __restrict__ rowptr, int* __restrict__ cursor,
    int N, int Etot)
{
    __shared__ int ls[256];
    int t = threadIdx.x;
    int chunk = (N + 255) / 256;
    int lo = t * chunk, hi = min(lo + chunk, N);
    int s = 0;
    for (int i = lo; i < hi; i++) s += cnt[i];
    ls[t] = s;
    __syncthreads();
    for (int off = 1; off < 256; off <<= 1) {
        int v = (t >= off) ? ls[t - off] : 0;
        __syncthreads();
        ls[t] += v;
        __syncthreads();
    }
    int run = ls[t] - s;
    for (int i = lo; i < hi; i++) {
        rowptr[i] = run; cursor[i] = run;
        run += cnt[i];
    }
    if (t == 0) rowptr[N] = Etot;
}

__global__ __launch_bounds__(256) void scatter_kernel(
    const int* __restrict__ srcA, const int* __restrict__ dstA,
    int* __restrict__ cursor, int* __restrict__ esrc, int* __restrict__ edst,
    int E, int Etot)
{
    for (int e = blockIdx.x * 256 + threadIdx.x; e < Etot; e += gridDim.x * 256) {
        int si = (e < E) ? srcA[e] : (e - E);
        int di = (e < E) ? dstA[e] : (e - E);
        int pos = atomicAdd(&cursor[di], 1);
        esrc[pos] = si;
        edst[pos] = di;
    }
}

// ---------------- edge scores via MFMA (CSR order), bf16 h source  [r11 proven version]
// planes: xi +0, xj +16384, d +32768 (plane = 64 rows x 256 B, XOR swizzle)
__global__ __launch_bounds__(256, 3) void edge_mfma_kernel(
    const unsigned* __restrict__ hbf,
    const int* __restrict__ esrc, const int* __restrict__ edst,
    const unsigned short* __restrict__ w1bf, const float* __restrict__ b1,
    const float* __restrict__ W2, const float* __restrict__ b2p,
    float* __restrict__ score, int Etot)
{
    __shared__ __align__(16) short sim[3][64][128];   // 48 KB
    __shared__ float pl[4][64];
    int tid = threadIdx.x, wv = tid >> 6, lane = tid & 63;
    char* simb = (char*)sim;

    short8 wf[12][2];
    {
        int ks = lane >> 4, c = lane & 15;
        #pragma unroll
        for (int q = 0; q < 12; q++)
            #pragma unroll
            for (int n = 0; n < 2; n++) {
                int ct = wv * 2 + n;
                wf[q][n] = *(const short8*)(w1bf + (size_t)(((q * 8 + ct) * 4 + ks) * 128 + c * 8));
            }
    }
    float b1x = b1[wv * 32 + (lane & 15)],  b1y = b1[wv * 32 + 16 + (lane & 15)];
    float w2x = W2[wv * 32 + (lane & 15)],  w2y = W2[wv * 32 + 16 + (lane & 15)];
    float b2 = b2p[0];

    int nb = gridDim.x;
    int swz = (blockIdx.x & 7) * (nb >> 3) + (blockIdx.x >> 3);
    int ntiles = (Etot + 63) >> 6;
    int t0 = (int)(((long long)ntiles * swz) / nb);
    int t1 = (int)(((long long)ntiles * (swz + 1)) / nb);
    if (t0 >= t1) return;

    int el = tid >> 2, seg = tid & 3;
    int e_cur = min((t0 << 6) + el, Etot - 1);
    int si = esrc[e_cur];
    int di = edst[e_cur];

    for (int tile = t0; tile < t1; tile++) {
        // ---- stage: all 8 row loads issued upfront (batched)
        const uint4* xi = (const uint4*)(hbf + (size_t)di * 64 + seg * 16);
        const uint4* xj = (const uint4*)(hbf + (size_t)si * 64 + seg * 16);
        uint4 a0 = xi[0], b0 = xj[0];
        uint4 a1 = xi[1], b1v = xj[1];
        uint4 a2 = xi[2], b2v = xj[2];
        uint4 a3 = xi[3], b3v = xj[3];
        // prefetch next tile's indices
        {
            int nt = (tile + 1 < t1) ? (tile + 1) : tile;
            int en = min((nt << 6) + el, Etot - 1);
            si = esrc[en];
            di = edst[en];
        }
        {
            int rowoff = el * 256, sw = (el & 7) << 4;
            uint4 d0, d1, d2, d3;
            d0.x = absd_bf2(a0.x, b0.x);  d0.y = absd_bf2(a0.y, b0.y);
            d0.z = absd_bf2(a0.z, b0.z);  d0.w = absd_bf2(a0.w, b0.w);
            d1.x = absd_bf2(a1.x, b1v.x); d1.y = absd_bf2(a1.y, b1v.y);
            d1.z = absd_bf2(a1.z, b1v.z); d1.w = absd_bf2(a1.w, b1v.w);
            d2.x = absd_bf2(a2.x, b2v.x); d2.y = absd_bf2(a2.y, b2v.y);
            d2.z = absd_bf2(a2.z, b2v.z); d2.w = absd_bf2(a2.w, b2v.w);
            d3.x = absd_bf2(a3.x, b3v.x); d3.y = absd_bf2(a3.y, b3v.y);
            d3.z = absd_bf2(a3.z, b3v.z); d3.w = absd_bf2(a3.w, b3v.w);
            int o0 = rowoff + ((seg * 64 +  0) ^ sw);
            int o1 = rowoff + ((seg * 64 + 16) ^ sw);
            int o2 = rowoff + ((seg * 64 + 32) ^ sw);
            int o3 = rowoff + ((seg * 64 + 48) ^ sw);
            *(uint4*)(simb + o0)         = a0;  *(uint4*)(simb + o1)         = a1;
            *(uint4*)(simb + o2)         = a2;  *(uint4*)(simb + o3)         = a3;
            *(uint4*)(simb + 16384 + o0) = b0;  *(uint4*)(simb + 16384 + o1) = b1v;
            *(uint4*)(simb + 16384 + o2) = b2v; *(uint4*)(simb + 16384 + o3) = b3v;
            *(uint4*)(simb + 32768 + o0) = d0;  *(uint4*)(simb + 32768 + o1) = d1;
            *(uint4*)(simb + 32768 + o2) = d2;  *(uint4*)(simb + 32768 + o3) = d3;
        }
        __syncthreads();
        f32x4 acc[4][2];
        #pragma unroll
        for (int m = 0; m < 4; m++)
            #pragma unroll
            for (int n = 0; n < 2; n++)
                #pragma unroll
                for (int r = 0; r < 4; r++) acc[m][n][r] = 0.f;
        __builtin_amdgcn_s_setprio(1);
        #pragma unroll
        for (int q = 0; q < 12; q++) {
            int third = q >> 2;
            int kin = ((q & 3) * 64 + (lane >> 4) * 16);
            short8 af[4];
            #pragma unroll
            for (int m = 0; m < 4; m++) {
                int elr = m * 16 + (lane & 15);
                int addr = third * 16384 + elr * 256 + (kin ^ ((elr & 7) << 4));
                af[m] = *(const short8*)(simb + addr);
            }
            #pragma unroll
            for (int m = 0; m < 4; m++)
                #pragma unroll
                for (int n = 0; n < 2; n++)
                    acc[m][n] = __builtin_amdgcn_mfma_f32_16x16x32_bf16(af[m], wf[q][n], acc[m][n], 0, 0, 0);
        }
        __builtin_amdgcn_s_setprio(0);
        int ebase = tile << 6;
        #pragma unroll
        for (int m = 0; m < 4; m++) {
            #pragma unroll
            for (int r = 0; r < 4; r++) {
                float v = fmaxf(acc[m][0][r] + b1x, 0.f) * w2x
                        + fmaxf(acc[m][1][r] + b1y, 0.f) * w2y;
                v += __shfl_xor(v, 1); v += __shfl_xor(v, 2);
                v += __shfl_xor(v, 4); v += __shfl_xor(v, 8);
                if ((lane & 15) == 0) pl[wv][m * 16 + (lane >> 4) * 4 + r] = v;
            }
        }
        __syncthreads();
        if (tid < 64) {
            int e = ebase + tid;
            if (e < Etot) {
                float z = pl[0][tid] + pl[1][tid] + pl[2][tid] + pl[3][tid] + b2;
                score[e] = 1.f / (1.f + __expf(-z));
            }
        }
    }
}

// ---------------- paggbf[n] = bf16( sum score[pos]*hbf[esrc[pos]] )  (fp32 accum)
__global__ __launch_bounds__(256) void gather_kernel(
    const int* __restrict__ rowptr, const int* __restrict__ esrc,
    const float* __restrict__ score, const unsigned* __restrict__ hbf,
    unsigned* __restrict__ paggbf, int N)
{
    int nb = gridDim.x;
    int bid = blockIdx.x;
    int swz = (bid & 7) * (nb >> 3) + (bid >> 3);
    int wvi = threadIdx.x >> 6, lane = threadIdx.x & 63;
    int node = swz * 4 + wvi;
    if (node >= N) return;
    int p0 = rowptr[node], p1 = rowptr[node + 1];
    float2 a0 = make_float2(0.f, 0.f), a1 = a0, a2 = a0, a3 = a0;
    for (int base = p0; base < p1; base += 64) {
        int cnt = min(64, p1 - base);
        int sidx = 0; float sc = 0.f;
        if (lane < cnt) {
            sidx = esrc[base + lane];
            sc = score[base + lane];
        }
        int i = 0;
        for (; i + 4 <= cnt; i += 4) {
            float s0 = __shfl(sc, i),     s1 = __shfl(sc, i + 1);
            float s2 = __shfl(sc, i + 2), s3 = __shfl(sc, i + 3);
            int r0 = __shfl(sidx, i),     r1 = __shfl(sidx, i + 1);
            int r2 = __shfl(sidx, i + 2), r3 = __shfl(sidx, i + 3);
            unsigned u0 = hbf[(size_t)r0 * 64 + lane];
            unsigned u1 = hbf[(size_t)r1 * 64 + lane];
            unsigned u2 = hbf[(size_t)r2 * 64 + lane];
            unsigned u3 = hbf[(size_t)r3 * 64 + lane];
            a0.x = fmaf(s0, __uint_as_float(u0 << 16), a0.x);
            a0.y = fmaf(s0, __uint_as_float(u0 & 0xffff0000u), a0.y);
            a1.x = fmaf(s1, __uint_as_float(u1 << 16), a1.x);
            a1.y = fmaf(s1, __uint_as_float(u1 & 0xffff0000u), a1.y);
            a2.x = fmaf(s2, __uint_as_float(u2 << 16), a2.x);
            a2.y = fmaf(s2, __uint_as_float(u2 & 0xffff0000u), a2.y);
            a3.x = fmaf(s3, __uint_as_float(u3 << 16), a3.x);
            a3.y = fmaf(s3, __uint_as_float(u3 & 0xffff0000u), a3.y);
        }
        for (; i < cnt; i++) {
            float s = __shfl(sc, i);
            int rr = __shfl(sidx, i);
            unsigned u = hbf[(size_t)rr * 64 + lane];
            a0.x = fmaf(s, __uint_as_float(u << 16), a0.x);
            a0.y = fmaf(s, __uint_as_float(u & 0xffff0000u), a0.y);
        }
    }
    float ox = (a0.x + a1.x) + (a2.x + a3.x);
    float oy = (a0.y + a1.y) + (a2.y + a3.y);
    paggbf[(size_t)node * 64 + lane] = cvtpk(ox, oy);
}

// ---------------- update via MFMA: h' = relu(LN(cat(hbf,paggbf)@wcbf + b + h))
// block = 64-node tile; wave wv owns cols [wv*32, wv*32+32).
__global__ __launch_bounds__(256, 3) void upd_mfma_kernel(
    const unsigned* __restrict__ hbf, const unsigned* __restrict__ paggbf,
    const float* __restrict__ hres,
    const unsigned short* __restrict__ wcbf,
    const float* __restrict__ bias, const float* __restrict__ g,
    const float* __restrict__ bln,
    float* __restrict__ hout, unsigned* __restrict__ hbf_out, int N)
{
    __shared__ float ps[4][64], pq[4][64];
    int tid = threadIdx.x, wv = tid >> 6, lane = tid & 63;
    int c = lane & 15, l16 = lane >> 4;
    int rbase = blockIdx.x * 64;
    if (rbase >= N) return;

    // B fragments: 8 q x 2 n (wave's 32 cols)
    short8 wf[8][2];
    #pragma unroll
    for (int q = 0; q < 8; q++)
        #pragma unroll
        for (int n = 0; n < 2; n++) {
            int ct = wv * 2 + n;
            wf[q][n] = *(const short8*)(wcbf + (size_t)(((q * 8 + ct) * 4 + l16) * 128 + c * 8));
        }
    float g0  = g[wv * 32 + c],    g1  = g[wv * 32 + 16 + c];
    float lb0 = bln[wv * 32 + c],  lb1 = bln[wv * 32 + 16 + c];
    float bs0 = bias[wv * 32 + c], bs1 = bias[wv * 32 + 16 + c];

    f32x4 acc[4][2];
    #pragma unroll
    for (int m = 0; m < 4; m++)
        #pragma unroll
        for (int n = 0; n < 2; n++)
            #pragma unroll
            for (int r = 0; r < 4; r++) acc[m][n][r] = 0.f;

    int arow[4];
    #pragma unroll
    for (int m = 0; m < 4; m++) arow[m] = min(rbase + m * 16 + c, N - 1);

    #pragma unroll
    for (int q = 0; q < 8; q++) {
        const unsigned* src = (q < 4) ? hbf : paggbf;
        int qq = (q < 4) ? q : q - 4;
        short8 af[4];
        #pragma unroll
        for (int m = 0; m < 4; m++)
            af[m] = *(const short8*)(src + (size_t)arow[m] * 64 + qq * 16 + l16 * 4);
        #pragma unroll
        for (int m = 0; m < 4; m++)
            #pragma unroll
            for (int n = 0; n < 2; n++)
                acc[m][n] = __builtin_amdgcn_mfma_f32_16x16x32_bf16(af[m], wf[q][n], acc[m][n], 0, 0, 0);
    }

    // bias + residual (fp32) + per-row partial sums over this wave's 32 cols
    #pragma unroll
    for (int m = 0; m < 4; m++) {
        #pragma unroll
        for (int r = 0; r < 4; r++) {
            int rit = m * 16 + l16 * 4 + r;
            int rowc = min(rbase + rit, N - 1);
            float v0 = acc[m][0][r] + bs0 + hres[(size_t)rowc * 128 + wv * 32 + c];
            float v1 = acc[m][1][r] + bs1 + hres[(size_t)rowc * 128 + wv * 32 + 16 + c];
            acc[m][0][r] = v0; acc[m][1][r] = v1;
            float s = v0 + v1, sq = v0 * v0 + v1 * v1;
            s  += __shfl_xor(s, 1);  s  += __shfl_xor(s, 2);  s  += __shfl_xor(s, 4);  s  += __shfl_xor(s, 8);
            sq += __shfl_xor(sq, 1); sq += __shfl_xor(sq, 2); sq += __shfl_xor(sq, 4); sq += __shfl_xor(sq, 8);
            if (c == 0) { ps[wv][rit] = s; pq[wv][rit] = sq; }
        }
    }
    __syncthreads();
    // LN + relu + stores (fp32 h + bf16 mirror via lane-pair exchange)
    #pragma unroll
    for (int m = 0; m < 4; m++) {
        #pragma unroll
        for (int r = 0; r < 4; r++) {
            int rit = m * 16 + l16 * 4 + r;
            int row = rbase + rit;
            float s  = (ps[0][rit] + ps[1][rit]) + (ps[2][rit] + ps[3][rit]);
            float sq = (pq[0][rit] + pq[1][rit]) + (pq[2][rit] + pq[3][rit]);
            float mu = s * (1.f / 128.f);
            float var = sq * (1.f / 128.f) - mu * mu;
            float rs = rsqrtf(var + LN_EPS);
            float y0 = fmaxf((acc[m][0][r] - mu) * rs * g0 + lb0, 0.f);
            float y1 = fmaxf((acc[m][1][r] - mu) * rs * g1 + lb1, 0.f);
            float z0 = __shfl_xor(y0, 1);
            float z1 = __shfl_xor(y1, 1);
            if (row < N) {
                hout[(size_t)row * 128 + wv * 32 + c]      = y0;
                hout[(size_t)row * 128 + wv * 32 + 16 + c] = y1;
                if (!(lane & 1)) {
                    hbf_out[(size_t)row * 64 + wv * 16 + (c >> 1)]     = cvtpk(y0, z0);
                    hbf_out[(size_t)row * 64 + wv * 16 + 8 + (c >> 1)] = cvtpk(y1, z1);
                }
            }
        }
    }
}

// ---------------- classifier
__global__ __launch_bounds__(256) void cls_kernel(
    const float* __restrict__ hin, const float* __restrict__ W1,
    const float* __restrict__ b1, const float* __restrict__ W2,
    const float* __restrict__ b2, float* __restrict__ out, int N)
{
    __shared__ __align__(16) float w1[HD * 64];
    __shared__ __align__(16) float w2[64 * 40];
    __shared__ __align__(16) float hs[4][HD];
    __shared__ float ts[4][64];
    for (int i = threadIdx.x; i < HD * 64; i += 256) w1[i] = W1[i];
    for (int i = threadIdx.x; i < 64 * 40; i += 256) w2[i] = W2[i];
    int sub = threadIdx.x >> 6, t = threadIdx.x & 63;
    float b1j = b1[t];
    float b2j = (t < 40) ? b2[t] : 0.f;
    __syncthreads();
    for (int base = blockIdx.x * 4; base < N; base += gridDim.x * 4) {
        int i = base + sub; bool val = i < N;
        if (val) { hs[sub][t] = hin[(size_t)i * HD + t]; hs[sub][64 + t] = hin[(size_t)i * HD + 64 + t]; }
        __syncthreads();
        float acc = b1j;
        const float* hr = hs[sub];
        #pragma unroll 8
        for (int k = 0; k < HD; k += 4) {
            float4 hv = *(const float4*)(hr + k);
            acc = fmaf(hv.x, w1[(k + 0) * 64 + t], acc);
            acc = fmaf(hv.y, w1[(k + 1) * 64 + t], acc);
            acc = fmaf(hv.z, w1[(k + 2) * 64 + t], acc);
            acc = fmaf(hv.w, w1[(k + 3) * 64 + t], acc);
        }
        ts[sub][t] = fmaxf(acc, 0.f);
        __syncthreads();
        if (val && t < 40) {
            float o = b2j;
            const float* tr = ts[sub];
            #pragma unroll 8
            for (int k = 0; k < 64; k++) o = fmaf(tr[k], w2[k * 40 + t], o);
            out[(size_t)i * 40 + t] = o;
        }
        __syncthreads();
    }
}

extern "C" void kernel_launch(void* const* d_in, const int* in_sizes, int n_in,
                              void* d_out, int out_size, void* d_ws, size_t ws_size,
                              hipStream_t stream)
{
    const float* x      = (const float*)d_in[0];
    const int*   ei     = (const int*)d_in[1];
    const float* proj_W = (const float*)d_in[2];
    const float* proj_b = (const float*)d_in[3];
    const float* ln0_g  = (const float*)d_in[4];
    const float* ln0_b  = (const float*)d_in[5];
    const float* sim_W1 = (const float*)d_in[6];
    const float* sim_b1 = (const float*)d_in[7];
    const float* sim_W2 = (const float*)d_in[8];
    const float* sim_b2 = (const float*)d_in[9];
    const float* W_msg  = (const float*)d_in[10];
    const float* W_upd  = (const float*)d_in[11];
    const float* b_upd  = (const float*)d_in[12];
    const float* ln_g   = (const float*)d_in[13];
    const float* ln_b   = (const float*)d_in[14];
    const float* cls_W1 = (const float*)d_in[15];
    const float* cls_b1 = (const float*)d_in[16];
    const float* cls_W2 = (const float*)d_in[17];
    const float* cls_b2 = (const float*)d_in[18];

    int N = in_sizes[0] / 256;
    int E = in_sizes[1] / 2;
    int L = in_sizes[6] / (3 * HD * HD);
    int Etot = E + N;
    const int* srcA = ei;
    const int* dstA = ei + E;

    float* ws = (float*)d_ws;
    size_t nh = (size_t)N * HD;
    float* h      = ws;
    float* score  = h + nh;
    float* wcomb  = score + Etot + 64;                        // L * 32768 floats
    unsigned* hbf    = (unsigned*)(wcomb + (size_t)L * 32768); // nh/2 uints
    unsigned* paggbf = hbf + nh / 2;                           // nh/2 uints
    unsigned short* w1bf = (unsigned short*)(paggbf + nh / 2); // L*49152 shorts
    unsigned short* wcbf = w1bf + (size_t)L * 49152;           // L*32768 shorts
    int*   cnt    = (int*)(wcbf + (size_t)L * 32768);
    int*   rowptr = cnt + N;
    int*   cursor = rowptr + N + 1;
    int*   esrc   = cursor + N;
    int*   edst   = esrc + Etot;

    int gemm_blocks = (N + 31) / 32;

    // CSR build (edge_index constant across layers)
    hipMemsetAsync(cnt, 0, (size_t)N * sizeof(int), stream);
    hist_kernel<<<512, 256, 0, stream>>>(dstA, cnt, E, Etot);
    scan_kernel<<<1, 256, 0, stream>>>(cnt, rowptr, cursor, N, Etot);
    scatter_kernel<<<512, 256, 0, stream>>>(srcA, dstA, cursor, esrc, edst, E, Etot);

    // W1 -> bf16 fragment-major (all layers, once)
    int w1_total = L * 49152;
    w1bf_kernel<<<(w1_total + 255) / 256, 256, 0, stream>>>(sim_W1, w1bf, w1_total);

    // wcomb[l] = [ W_upd[l][0:128] ; W_msg[l] @ W_upd[l][128:256] ]  (fp32)
    int cp_total = L * 16384;
    copy_upd_kernel<<<(cp_total + 255) / 256, 256, 0, stream>>>(W_upd, wcomb, cp_total);
    for (int l = 0; l < L; l++) {
        gemm_rows_kernel<<<(128 + 31) / 32, 256, 0, stream>>>(
            W_msg + (size_t)l * 16384, 128, nullptr, 0,
            W_upd + (size_t)l * 32768 + 16384, nullptr, nullptr, nullptr, nullptr,
            wcomb + (size_t)l * 32768 + 16384, nullptr, 128);
    }
    // wcomb -> bf16 fragment-major
    int wc_total = L * 32768;
    wcbf_kernel<<<(wc_total + 255) / 256, 256, 0, stream>>>(wcomb, wcbf, wc_total);

    // h = relu(LN(x @ proj_W + b)), hbf mirror
    gemm_rows_kernel<<<gemm_blocks, 256, 0, stream>>>(x, 256, x + 128, 256, proj_W, proj_b,
                                                      nullptr, ln0_g, ln0_b, h, hbf, N);

    int gather_blocks = (N + 3) / 4;          // 5000, divisible by 8
    int upd_blocks = (N + 63) / 64;
    for (int l = 0; l < L; l++) {
        edge_mfma_kernel<<<768, 256, 0, stream>>>(hbf, esrc, edst,
                                                  w1bf + (size_t)l * 49152, sim_b1 + l * HD,
                                                  sim_W2 + l * HD, sim_b2 + l, score, Etot);
        gather_kernel<<<gather_blocks, 256, 0, stream>>>(rowptr, esrc, score, hbf, paggbf, N);
        upd_mfma_kernel<<<upd_blocks, 256, 0, stream>>>(hbf, paggbf, h,
                                                        wcbf + (size_t)l * 32768,
                                                        b_upd + l * HD, ln_g + l * HD, ln_b + l * HD,
                                                        h, hbf, N);
    }
    cls_kernel<<<768, 256, 0, stream>>>(h, cls_W1, cls_b1, cls_W2, cls_b2, (float*)d_out, N);
}

// Round 14
// 420.298 us; speedup vs baseline: 1.2880x; 1.0819x over previous
//
#include <hip/hip_runtime.h>
#include <hip/hip_bf16.h>

#define HD 128
#define LN_EPS 1e-5f

typedef __attribute__((ext_vector_type(8))) short short8;
typedef __attribute__((ext_vector_type(4))) float f32x4;

__device__ __forceinline__ unsigned short f2bf(float f) {
    union { float f; unsigned u; } v; v.f = f;
    unsigned r = (v.u + 0x7fffu + ((v.u >> 16) & 1u)) >> 16;
    return (unsigned short)r;
}

__device__ __forceinline__ unsigned cvtpk(float lo, float hi) {
    unsigned r;
    asm("v_cvt_pk_bf16_f32 %0, %1, %2" : "=v"(r) : "v"(lo), "v"(hi));
    return r;
}
__device__ __forceinline__ unsigned cvtpk_abs(float lo, float hi) {
    unsigned r;
    asm("v_cvt_pk_bf16_f32 %0, abs(%1), abs(%2)" : "=v"(r) : "v"(lo), "v"(hi));
    return r;
}
// packed |a-b| on bf16 pairs -> packed bf16
__device__ __forceinline__ unsigned absd_bf2(unsigned a, unsigned b) {
    float alo = __uint_as_float(a << 16), ahi = __uint_as_float(a & 0xffff0000u);
    float blo = __uint_as_float(b << 16), bhi = __uint_as_float(b & 0xffff0000u);
    return cvtpk_abs(alo - blo, ahi - bhi);
}
__device__ __forceinline__ float bflo(unsigned u) { return __uint_as_float(u << 16); }
__device__ __forceinline__ float bfhi(unsigned u) { return __uint_as_float(u & 0xffff0000u); }

__device__ __forceinline__ float wave_sum_all(float v) {
    #pragma unroll
    for (int o = 32; o > 0; o >>= 1) v += __shfl_xor(v, o);
    return v;
}

// ---------------- W1 (L x 384x128 f32) -> bf16 fragment-major, all layers
__global__ __launch_bounds__(256) void w1bf_kernel(
    const float* __restrict__ W1, unsigned short* __restrict__ out, int total)
{
    int idx = blockIdx.x * 256 + threadIdx.x;
    if (idx >= total) return;
    int lw  = idx / 49152;
    int rem = idx - lw * 49152;
    int j  = rem & 7;
    int c  = (rem >> 3) & 15;
    int ks = (rem >> 7) & 3;
    int ct = (rem >> 9) & 7;
    int q  = rem >> 12;
    out[idx] = f2bf(W1[(size_t)lw * 49152 + (size_t)(q * 32 + ks * 8 + j) * 128 + ct * 16 + c]);
}

// ---------------- wcomb bf16 fragment-major; rows 0..127 from W_upd[l][0:128],
// rows 128..255 from wcomb2[l] = W_msg[l] @ W_upd[l][128:256]
__global__ __launch_bounds__(256) void wcbf_kernel(
    const float* __restrict__ W_upd, const float* __restrict__ wcomb2,
    unsigned short* __restrict__ out, int total)
{
    int idx = blockIdx.x * 256 + threadIdx.x;
    if (idx >= total) return;
    int lw  = idx >> 15;            // / 32768
    int rem = idx & 32767;
    int j  = rem & 7;
    int c  = (rem >> 3) & 15;
    int ks = (rem >> 7) & 3;
    int ct = (rem >> 9) & 7;
    int q  = rem >> 12;             // 0..7
    int row = q * 32 + ks * 8 + j;
    int col = ct * 16 + c;
    float v = (row < 128) ? W_upd[(size_t)lw * 32768 + (size_t)row * 128 + col]
                          : wcomb2[(size_t)lw * 16384 + (size_t)(row - 128) * 128 + col];
    out[idx] = f2bf(v);
}

// ---------------- wcomb2[l] = W_msg[l] @ W_upd[l][128:256], batched over l (4 blocks/l)
__global__ __launch_bounds__(256) void wmsg_gemm_kernel(
    const float* __restrict__ W_msg, const float* __restrict__ W_upd,
    float* __restrict__ wcomb2)
{
    __shared__ __align__(16) float rows[4][8][128];
    int l   = blockIdx.x >> 2;
    int blk = blockIdx.x & 3;
    const float* A = W_msg + (size_t)l * 16384;
    const float* W = W_upd + (size_t)l * 32768 + 16384;
    float* out = wcomb2 + (size_t)l * 16384;
    int tid = threadIdx.x, wv = tid >> 6, lane = tid & 63;
    int rbase = (blk * 4 + wv) * 8;
    int r = lane >> 3, seg = lane & 7;
    {
        const float2* p = (const float2*)(A + (size_t)(rbase + r) * 128 + seg * 16);
        float2* q = (float2*)&rows[wv][r][seg * 16];
        #pragma unroll
        for (int i = 0; i < 8; i++) q[i] = p[i];
    }
    asm volatile("s_waitcnt lgkmcnt(0)" ::: "memory");
    float2 acc[8];
    #pragma unroll
    for (int t = 0; t < 8; t++) acc[t] = make_float2(0.f, 0.f);
    for (int k = 0; k < 128; k += 4) {
        float2 w0 = *(const float2*)(W + (size_t)(k + 0) * 128 + 2 * lane);
        float2 w1 = *(const float2*)(W + (size_t)(k + 1) * 128 + 2 * lane);
        float2 w2 = *(const float2*)(W + (size_t)(k + 2) * 128 + 2 * lane);
        float2 w3 = *(const float2*)(W + (size_t)(k + 3) * 128 + 2 * lane);
        #pragma unroll
        for (int t = 0; t < 8; t++) {
            float4 a = *(const float4*)&rows[wv][t][k];
            acc[t].x = fmaf(a.x, w0.x, acc[t].x); acc[t].y = fmaf(a.x, w0.y, acc[t].y);
            acc[t].x = fmaf(a.y, w1.x, acc[t].x); acc[t].y = fmaf(a.y, w1.y, acc[t].y);
            acc[t].x = fmaf(a.z, w2.x, acc[t].x); acc[t].y = fmaf(a.z, w2.y, acc[t].y);
            acc[t].x = fmaf(a.w, w3.x, acc[t].x); acc[t].y = fmaf(a.w, w3.y, acc[t].y);
        }
    }
    #pragma unroll
    for (int t = 0; t < 8; t++)
        *(float2*)(out + (size_t)(rbase + t) * 128 + 2 * lane) = acc[t];
}

// ---------------- fp32 GEMM: out[N][128] = cat(in0,in1)[N][K] @ W[K][128] (+bias)(+res)
// optional fused LN+relu epilogue (g != nullptr); optional bf16 mirror store (out_bf).
__global__ __launch_bounds__(256) void gemm_rows_kernel(
    const float* __restrict__ in0, int s0, const float* __restrict__ in1, int s1,
    const float* __restrict__ W, const float* __restrict__ bias,
    const float* __restrict__ res, const float* __restrict__ g,
    const float* __restrict__ bln, float* __restrict__ out,
    unsigned* __restrict__ out_bf, int N)
{
    __shared__ __align__(16) float rows[4][8][256];
    int tid = threadIdx.x, wv = tid >> 6, lane = tid & 63;
    int rbase = (blockIdx.x * 4 + wv) * 8;
    if (rbase >= N) return;
    int K = in1 ? 256 : 128;
    int r = lane >> 3, seg = lane & 7;
    int row = min(rbase + r, N - 1);
    {
        const float4* p = (const float4*)(in0 + (size_t)row * s0 + seg * 16);
        float4* q = (float4*)&rows[wv][r][seg * 16];
        #pragma unroll
        for (int i = 0; i < 4; i++) q[i] = p[i];
        if (in1) {
            const float4* p1 = (const float4*)(in1 + (size_t)row * s1 + seg * 16);
            float4* q1 = (float4*)&rows[wv][r][128 + seg * 16];
            #pragma unroll
            for (int i = 0; i < 4; i++) q1[i] = p1[i];
        }
    }
    asm volatile("s_waitcnt lgkmcnt(0)" ::: "memory");
    float2 acc[8];
    float2 bv = make_float2(0.f, 0.f);
    if (bias) bv = *(const float2*)(bias + 2 * lane);
    #pragma unroll
    for (int t = 0; t < 8; t++) acc[t] = bv;
    for (int k = 0; k < K; k += 4) {
        float2 w0 = *(const float2*)(W + (size_t)(k + 0) * 128 + 2 * lane);
        float2 w1 = *(const float2*)(W + (size_t)(k + 1) * 128 + 2 * lane);
        float2 w2 = *(const float2*)(W + (size_t)(k + 2) * 128 + 2 * lane);
        float2 w3 = *(const float2*)(W + (size_t)(k + 3) * 128 + 2 * lane);
        #pragma unroll
        for (int t = 0; t < 8; t++) {
            float4 a = *(const float4*)&rows[wv][t][k];
            acc[t].x = fmaf(a.x, w0.x, acc[t].x); acc[t].y = fmaf(a.x, w0.y, acc[t].y);
            acc[t].x = fmaf(a.y, w1.x, acc[t].x); acc[t].y = fmaf(a.y, w1.y, acc[t].y);
            acc[t].x = fmaf(a.z, w2.x, acc[t].x); acc[t].y = fmaf(a.z, w2.y, acc[t].y);
            acc[t].x = fmaf(a.w, w3.x, acc[t].x); acc[t].y = fmaf(a.w, w3.y, acc[t].y);
        }
    }
    if (res) {
        #pragma unroll
        for (int t = 0; t < 8; t++) {
            int rw = rbase + t;
            if (rw < N) {
                float2 rv = *(const float2*)(res + (size_t)rw * 128 + 2 * lane);
                acc[t].x += rv.x; acc[t].y += rv.y;
            }
        }
    }
    if (g) {
        float2 gv = *(const float2*)(g + 2 * lane);
        float2 lv = *(const float2*)(bln + 2 * lane);
        #pragma unroll
        for (int t = 0; t < 8; t++) {
            int rw = rbase + t;
            if (rw >= N) break;
            float s  = wave_sum_all(acc[t].x + acc[t].y);
            float s2 = wave_sum_all(acc[t].x * acc[t].x + acc[t].y * acc[t].y);
            float mu = s * (1.f / 128.f);
            float var = s2 * (1.f / 128.f) - mu * mu;
            float rs = rsqrtf(var + LN_EPS);
            float2 y;
            y.x = fmaxf((acc[t].x - mu) * rs * gv.x + lv.x, 0.f);
            y.y = fmaxf((acc[t].y - mu) * rs * gv.y + lv.y, 0.f);
            *(float2*)(out + (size_t)rw * 128 + 2 * lane) = y;
            if (out_bf) out_bf[(size_t)rw * 64 + lane] = cvtpk(y.x, y.y);
        }
    } else {
        #pragma unroll
        for (int t = 0; t < 8; t++) {
            int rw = rbase + t;
            if (rw < N) *(float2*)(out + (size_t)rw * 128 + 2 * lane) = acc[t];
        }
    }
}

// ---------------- CSR build ----------------
__global__ __launch_bounds__(256) void hist_kernel(
    const int* __restrict__ dstA, int* __restrict__ cnt, int E, int Etot)
{
    for (int e = blockIdx.x * 256 + threadIdx.x; e < Etot; e += gridDim.x * 256) {
        int di = (e < E) ? dstA[e] : (e - E);
        atomicAdd(&cnt[di], 1);
    }
}

__global__ __launch_bounds__(256) void scan_kernel(
    const int* __restrict__ cnt, int* __restrict__ rowptr, int* __restrict__ cursor,
    int N, int Etot)
{
    __shared__ int ls[256];
    int t = threadIdx.x;
    int chunk = (N + 255) / 256;
    int lo = t * chunk, hi = min(lo + chunk, N);
    int s = 0;
    for (int i = lo; i < hi; i++) s += cnt[i];
    ls[t] = s;
    __syncthreads();
    for (int off = 1; off < 256; off <<= 1) {
        int v = (t >= off) ? ls[t - off] : 0;
        __syncthreads();
        ls[t] += v;
        __syncthreads();
    }
    int run = ls[t] - s;
    for (int i = lo; i < hi; i++) {
        rowptr[i] = run; cursor[i] = run;
        run += cnt[i];
    }
    if (t == 0) rowptr[N] = Etot;
}

__global__ __launch_bounds__(256) void scatter_kernel(
    const int* __restrict__ srcA, const int* __restrict__ dstA,
    int* __restrict__ cursor, int* __restrict__ esrc, int* __restrict__ edst,
    int E, int Etot)
{
    for (int e = blockIdx.x * 256 + threadIdx.x; e < Etot; e += gridDim.x * 256) {
        int si = (e < E) ? srcA[e] : (e - E);
        int di = (e < E) ? dstA[e] : (e - E);
        int pos = atomicAdd(&cursor[di], 1);
        esrc[pos] = si;
        edst[pos] = di;
    }
}

// ---------------- edge scores via MFMA (CSR order), bf16 h source  [r11 proven version]
// planes: xi +0, xj +16384, d +32768 (plane = 64 rows x 256 B, XOR swizzle)
__global__ __launch_bounds__(256, 3) void edge_mfma_kernel(
    const unsigned* __restrict__ hbf,
    const int* __restrict__ esrc, const int* __restrict__ edst,
    const unsigned short* __restrict__ w1bf, const float* __restrict__ b1,
    const float* __restrict__ W2, const float* __restrict__ b2p,
    float* __restrict__ score, int Etot)
{
    __shared__ __align__(16) short sim[3][64][128];   // 48 KB
    __shared__ float pl[4][64];
    int tid = threadIdx.x, wv = tid >> 6, lane = tid & 63;
    char* simb = (char*)sim;

    short8 wf[12][2];
    {
        int ks = lane >> 4, c = lane & 15;
        #pragma unroll
        for (int q = 0; q < 12; q++)
            #pragma unroll
            for (int n = 0; n < 2; n++) {
                int ct = wv * 2 + n;
                wf[q][n] = *(const short8*)(w1bf + (size_t)(((q * 8 + ct) * 4 + ks) * 128 + c * 8));
            }
    }
    float b1x = b1[wv * 32 + (lane & 15)],  b1y = b1[wv * 32 + 16 + (lane & 15)];
    float w2x = W2[wv * 32 + (lane & 15)],  w2y = W2[wv * 32 + 16 + (lane & 15)];
    float b2 = b2p[0];

    int nb = gridDim.x;
    int swz = (blockIdx.x & 7) * (nb >> 3) + (blockIdx.x >> 3);
    int ntiles = (Etot + 63) >> 6;
    int t0 = (int)(((long long)ntiles * swz) / nb);
    int t1 = (int)(((long long)ntiles * (swz + 1)) / nb);
    if (t0 >= t1) return;

    int el = tid >> 2, seg = tid & 3;
    int e_cur = min((t0 << 6) + el, Etot - 1);
    int si = esrc[e_cur];
    int di = edst[e_cur];

    for (int tile = t0; tile < t1; tile++) {
        // ---- stage: all 8 row loads issued upfront (batched)
        const uint4* xi = (const uint4*)(hbf + (size_t)di * 64 + seg * 16);
        const uint4* xj = (const uint4*)(hbf + (size_t)si * 64 + seg * 16);
        uint4 a0 = xi[0], b0 = xj[0];
        uint4 a1 = xi[1], b1v = xj[1];
        uint4 a2 = xi[2], b2v = xj[2];
        uint4 a3 = xi[3], b3v = xj[3];
        // prefetch next tile's indices
        {
            int nt = (tile + 1 < t1) ? (tile + 1) : tile;
            int en = min((nt << 6) + el, Etot - 1);
            si = esrc[en];
            di = edst[en];
        }
        {
            int rowoff = el * 256, sw = (el & 7) << 4;
            uint4 d0, d1, d2, d3;
            d0.x = absd_bf2(a0.x, b0.x);  d0.y = absd_bf2(a0.y, b0.y);
            d0.z = absd_bf2(a0.z, b0.z);  d0.w = absd_bf2(a0.w, b0.w);
            d1.x = absd_bf2(a1.x, b1v.x); d1.y = absd_bf2(a1.y, b1v.y);
            d1.z = absd_bf2(a1.z, b1v.z); d1.w = absd_bf2(a1.w, b1v.w);
            d2.x = absd_bf2(a2.x, b2v.x); d2.y = absd_bf2(a2.y, b2v.y);
            d2.z = absd_bf2(a2.z, b2v.z); d2.w = absd_bf2(a2.w, b2v.w);
            d3.x = absd_bf2(a3.x, b3v.x); d3.y = absd_bf2(a3.y, b3v.y);
            d3.z = absd_bf2(a3.z, b3v.z); d3.w = absd_bf2(a3.w, b3v.w);
            int o0 = rowoff + ((seg * 64 +  0) ^ sw);
            int o1 = rowoff + ((seg * 64 + 16) ^ sw);
            int o2 = rowoff + ((seg * 64 + 32) ^ sw);
            int o3 = rowoff + ((seg * 64 + 48) ^ sw);
            *(uint4*)(simb + o0)         = a0;  *(uint4*)(simb + o1)         = a1;
            *(uint4*)(simb + o2)         = a2;  *(uint4*)(simb + o3)         = a3;
            *(uint4*)(simb + 16384 + o0) = b0;  *(uint4*)(simb + 16384 + o1) = b1v;
            *(uint4*)(simb + 16384 + o2) = b2v; *(uint4*)(simb + 16384 + o3) = b3v;
            *(uint4*)(simb + 32768 + o0) = d0;  *(uint4*)(simb + 32768 + o1) = d1;
            *(uint4*)(simb + 32768 + o2) = d2;  *(uint4*)(simb + 32768 + o3) = d3;
        }
        __syncthreads();
        f32x4 acc[4][2];
        #pragma unroll
        for (int m = 0; m < 4; m++)
            #pragma unroll
            for (int n = 0; n < 2; n++)
                #pragma unroll
                for (int r = 0; r < 4; r++) acc[m][n][r] = 0.f;
        __builtin_amdgcn_s_setprio(1);
        #pragma unroll
        for (int q = 0; q < 12; q++) {
            int third = q >> 2;
            int kin = ((q & 3) * 64 + (lane >> 4) * 16);
            short8 af[4];
            #pragma unroll
            for (int m = 0; m < 4; m++) {
                int elr = m * 16 + (lane & 15);
                int addr = third * 16384 + elr * 256 + (kin ^ ((elr & 7) << 4));
                af[m] = *(const short8*)(simb + addr);
            }
            #pragma unroll
            for (int m = 0; m < 4; m++)
                #pragma unroll
                for (int n = 0; n < 2; n++)
                    acc[m][n] = __builtin_amdgcn_mfma_f32_16x16x32_bf16(af[m], wf[q][n], acc[m][n], 0, 0, 0);
        }
        __builtin_amdgcn_s_setprio(0);
        int ebase = tile << 6;
        #pragma unroll
        for (int m = 0; m < 4; m++) {
            #pragma unroll
            for (int r = 0; r < 4; r++) {
                float v = fmaxf(acc[m][0][r] + b1x, 0.f) * w2x
                        + fmaxf(acc[m][1][r] + b1y, 0.f) * w2y;
                v += __shfl_xor(v, 1); v += __shfl_xor(v, 2);
                v += __shfl_xor(v, 4); v += __shfl_xor(v, 8);
                if ((lane & 15) == 0) pl[wv][m * 16 + (lane >> 4) * 4 + r] = v;
            }
        }
        __syncthreads();
        if (tid < 64) {
            int e = ebase + tid;
            if (e < Etot) {
                float z = pl[0][tid] + pl[1][tid] + pl[2][tid] + pl[3][tid] + b2;
                score[e] = 1.f / (1.f + __expf(-z));
            }
        }
    }
}

// ---------------- paggbf[n] = bf16( sum score[pos]*hbf[esrc[pos]] )  (fp32 accum)
// uint2 per lane over 32 lanes/row; lane-halves process two rows per step -> 8 rows in flight.
__global__ __launch_bounds__(256) void gather_kernel(
    const int* __restrict__ rowptr, const int* __restrict__ esrc,
    const float* __restrict__ score, const unsigned* __restrict__ hbf,
    unsigned* __restrict__ paggbf, int N)
{
    int nb = gridDim.x;
    int bid = blockIdx.x;
    int swz = (bid & 7) * (nb >> 3) + (bid >> 3);
    int wvi = threadIdx.x >> 6, lane = threadIdx.x & 63;
    int node = swz * 4 + wvi;
    if (node >= N) return;
    int p0 = rowptr[node], p1 = rowptr[node + 1];
    int half = lane >> 5, l32 = lane & 31;
    const uint2* hb2 = (const uint2*)hbf;
    float4 c0 = make_float4(0.f, 0.f, 0.f, 0.f), c1 = c0, c2 = c0, c3 = c0;
    for (int base = p0; base < p1; base += 64) {
        int cnt = min(64, p1 - base);
        int sidx = 0; float sc = 0.f;
        if (lane < cnt) {
            sidx = esrc[base + lane];
            sc = score[base + lane];
        }
        for (int i = 0; i < cnt; i += 8) {
            int j0 = i + 0 + half, j1 = i + 2 + half, j2 = i + 4 + half, j3 = i + 6 + half;
            float s0 = __shfl(sc, j0), s1 = __shfl(sc, j1);
            float s2 = __shfl(sc, j2), s3 = __shfl(sc, j3);
            int r0 = __shfl(sidx, j0), r1 = __shfl(sidx, j1);
            int r2 = __shfl(sidx, j2), r3 = __shfl(sidx, j3);
            if (j0 >= cnt) s0 = 0.f;
            if (j1 >= cnt) s1 = 0.f;
            if (j2 >= cnt) s2 = 0.f;
            if (j3 >= cnt) s3 = 0.f;
            uint2 u0 = hb2[(size_t)r0 * 32 + l32];
            uint2 u1 = hb2[(size_t)r1 * 32 + l32];
            uint2 u2 = hb2[(size_t)r2 * 32 + l32];
            uint2 u3 = hb2[(size_t)r3 * 32 + l32];
            c0.x = fmaf(s0, bflo(u0.x), c0.x); c0.y = fmaf(s0, bfhi(u0.x), c0.y);
            c0.z = fmaf(s0, bflo(u0.y), c0.z); c0.w = fmaf(s0, bfhi(u0.y), c0.w);
            c1.x = fmaf(s1, bflo(u1.x), c1.x); c1.y = fmaf(s1, bfhi(u1.x), c1.y);
            c1.z = fmaf(s1, bflo(u1.y), c1.z); c1.w = fmaf(s1, bfhi(u1.y), c1.w);
            c2.x = fmaf(s2, bflo(u2.x), c2.x); c2.y = fmaf(s2, bfhi(u2.x), c2.y);
            c2.z = fmaf(s2, bflo(u2.y), c2.z); c2.w = fmaf(s2, bfhi(u2.y), c2.w);
            c3.x = fmaf(s3, bflo(u3.x), c3.x); c3.y = fmaf(s3, bfhi(u3.x), c3.y);
            c3.z = fmaf(s3, bflo(u3.y), c3.z); c3.w = fmaf(s3, bfhi(u3.y), c3.w);
        }
    }
    float4 t;
    t.x = (c0.x + c1.x) + (c2.x + c3.x);
    t.y = (c0.y + c1.y) + (c2.y + c3.y);
    t.z = (c0.z + c1.z) + (c2.z + c3.z);
    t.w = (c0.w + c1.w) + (c2.w + c3.w);
    t.x += __shfl_xor(t.x, 32);
    t.y += __shfl_xor(t.y, 32);
    t.z += __shfl_xor(t.z, 32);
    t.w += __shfl_xor(t.w, 32);
    if (half == 0) {
        uint2 o;
        o.x = cvtpk(t.x, t.y);
        o.y = cvtpk(t.z, t.w);
        ((uint2*)paggbf)[(size_t)node * 32 + l32] = o;
    }
}

// ---------------- update via MFMA: h' = relu(LN(cat(hbf,paggbf)@wcbf + b + h))
// block = 64-node tile; wave wv owns cols [wv*32, wv*32+32).
__global__ __launch_bounds__(256, 3) void upd_mfma_kernel(
    const unsigned* __restrict__ hbf, const unsigned* __restrict__ paggbf,
    const float* __restrict__ hres,
    const unsigned short* __restrict__ wcbf,
    const float* __restrict__ bias, const float* __restrict__ g,
    const float* __restrict__ bln,
    float* __restrict__ hout, unsigned* __restrict__ hbf_out, int N)
{
    __shared__ float ps[4][64], pq[4][64];
    int tid = threadIdx.x, wv = tid >> 6, lane = tid & 63;
    int c = lane & 15, l16 = lane >> 4;
    int rbase = blockIdx.x * 64;
    if (rbase >= N) return;

    short8 wf[8][2];
    #pragma unroll
    for (int q = 0; q < 8; q++)
        #pragma unroll
        for (int n = 0; n < 2; n++) {
            int ct = wv * 2 + n;
            wf[q][n] = *(const short8*)(wcbf + (size_t)(((q * 8 + ct) * 4 + l16) * 128 + c * 8));
        }
    float g0  = g[wv * 32 + c],    g1  = g[wv * 32 + 16 + c];
    float lb0 = bln[wv * 32 + c],  lb1 = bln[wv * 32 + 16 + c];
    float bs0 = bias[wv * 32 + c], bs1 = bias[wv * 32 + 16 + c];

    f32x4 acc[4][2];
    #pragma unroll
    for (int m = 0; m < 4; m++)
        #pragma unroll
        for (int n = 0; n < 2; n++)
            #pragma unroll
            for (int r = 0; r < 4; r++) acc[m][n][r] = 0.f;

    int arow[4];
    #pragma unroll
    for (int m = 0; m < 4; m++) arow[m] = min(rbase + m * 16 + c, N - 1);

    #pragma unroll
    for (int q = 0; q < 8; q++) {
        const unsigned* src = (q < 4) ? hbf : paggbf;
        int qq = (q < 4) ? q : q - 4;
        short8 af[4];
        #pragma unroll
        for (int m = 0; m < 4; m++)
            af[m] = *(const short8*)(src + (size_t)arow[m] * 64 + qq * 16 + l16 * 4);
        #pragma unroll
        for (int m = 0; m < 4; m++)
            #pragma unroll
            for (int n = 0; n < 2; n++)
                acc[m][n] = __builtin_amdgcn_mfma_f32_16x16x32_bf16(af[m], wf[q][n], acc[m][n], 0, 0, 0);
    }

    #pragma unroll
    for (int m = 0; m < 4; m++) {
        #pragma unroll
        for (int r = 0; r < 4; r++) {
            int rit = m * 16 + l16 * 4 + r;
            int rowc = min(rbase + rit, N - 1);
            float v0 = acc[m][0][r] + bs0 + hres[(size_t)rowc * 128 + wv * 32 + c];
            float v1 = acc[m][1][r] + bs1 + hres[(size_t)rowc * 128 + wv * 32 + 16 + c];
            acc[m][0][r] = v0; acc[m][1][r] = v1;
            float s = v0 + v1, sq = v0 * v0 + v1 * v1;
            s  += __shfl_xor(s, 1);  s  += __shfl_xor(s, 2);  s  += __shfl_xor(s, 4);  s  += __shfl_xor(s, 8);
            sq += __shfl_xor(sq, 1); sq += __shfl_xor(sq, 2); sq += __shfl_xor(sq, 4); sq += __shfl_xor(sq, 8);
            if (c == 0) { ps[wv][rit] = s; pq[wv][rit] = sq; }
        }
    }
    __syncthreads();
    #pragma unroll
    for (int m = 0; m < 4; m++) {
        #pragma unroll
        for (int r = 0; r < 4; r++) {
            int rit = m * 16 + l16 * 4 + r;
            int row = rbase + rit;
            float s  = (ps[0][rit] + ps[1][rit]) + (ps[2][rit] + ps[3][rit]);
            float sq = (pq[0][rit] + pq[1][rit]) + (pq[2][rit] + pq[3][rit]);
            float mu = s * (1.f / 128.f);
            float var = sq * (1.f / 128.f) - mu * mu;
            float rs = rsqrtf(var + LN_EPS);
            float y0 = fmaxf((acc[m][0][r] - mu) * rs * g0 + lb0, 0.f);
            float y1 = fmaxf((acc[m][1][r] - mu) * rs * g1 + lb1, 0.f);
            float z0 = __shfl_xor(y0, 1);
            float z1 = __shfl_xor(y1, 1);
            if (row < N) {
                hout[(size_t)row * 128 + wv * 32 + c]      = y0;
                hout[(size_t)row * 128 + wv * 32 + 16 + c] = y1;
                if (!(lane & 1)) {
                    hbf_out[(size_t)row * 64 + wv * 16 + (c >> 1)]     = cvtpk(y0, z0);
                    hbf_out[(size_t)row * 64 + wv * 16 + 8 + (c >> 1)] = cvtpk(y1, z1);
                }
            }
        }
    }
}

// ---------------- classifier
__global__ __launch_bounds__(256) void cls_kernel(
    const float* __restrict__ hin, const float* __restrict__ W1,
    const float* __restrict__ b1, const float* __restrict__ W2,
    const float* __restrict__ b2, float* __restrict__ out, int N)
{
    __shared__ __align__(16) float w1[HD * 64];
    __shared__ __align__(16) float w2[64 * 40];
    __shared__ __align__(16) float hs[4][HD];
    __shared__ float ts[4][64];
    for (int i = threadIdx.x; i < HD * 64; i += 256) w1[i] = W1[i];
    for (int i = threadIdx.x; i < 64 * 40; i += 256) w2[i] = W2[i];
    int sub = threadIdx.x >> 6, t = threadIdx.x & 63;
    float b1j = b1[t];
    float b2j = (t < 40) ? b2[t] : 0.f;
    __syncthreads();
    for (int base = blockIdx.x * 4; base < N; base += gridDim.x * 4) {
        int i = base + sub; bool val = i < N;
        if (val) { hs[sub][t] = hin[(size_t)i * HD + t]; hs[sub][64 + t] = hin[(size_t)i * HD + 64 + t]; }
        __syncthreads();
        float acc = b1j;
        const float* hr = hs[sub];
        #pragma unroll 8
        for (int k = 0; k < HD; k += 4) {
            float4 hv = *(const float4*)(hr + k);
            acc = fmaf(hv.x, w1[(k + 0) * 64 + t], acc);
            acc = fmaf(hv.y, w1[(k + 1) * 64 + t], acc);
            acc = fmaf(hv.z, w1[(k + 2) * 64 + t], acc);
            acc = fmaf(hv.w, w1[(k + 3) * 64 + t], acc);
        }
        ts[sub][t] = fmaxf(acc, 0.f);
        __syncthreads();
        if (val && t < 40) {
            float o = b2j;
            const float* tr = ts[sub];
            #pragma unroll 8
            for (int k = 0; k < 64; k++) o = fmaf(tr[k], w2[k * 40 + t], o);
            out[(size_t)i * 40 + t] = o;
        }
        __syncthreads();
    }
}

extern "C" void kernel_launch(void* const* d_in, const int* in_sizes, int n_in,
                              void* d_out, int out_size, void* d_ws, size_t ws_size,
                              hipStream_t stream)
{
    const float* x      = (const float*)d_in[0];
    const int*   ei     = (const int*)d_in[1];
    const float* proj_W = (const float*)d_in[2];
    const float* proj_b = (const float*)d_in[3];
    const float* ln0_g  = (const float*)d_in[4];
    const float* ln0_b  = (const float*)d_in[5];
    const float* sim_W1 = (const float*)d_in[6];
    const float* sim_b1 = (const float*)d_in[7];
    const float* sim_W2 = (const float*)d_in[8];
    const float* sim_b2 = (const float*)d_in[9];
    const float* W_msg  = (const float*)d_in[10];
    const float* W_upd  = (const float*)d_in[11];
    const float* b_upd  = (const float*)d_in[12];
    const float* ln_g   = (const float*)d_in[13];
    const float* ln_b   = (const float*)d_in[14];
    const float* cls_W1 = (const float*)d_in[15];
    const float* cls_b1 = (const float*)d_in[16];
    const float* cls_W2 = (const float*)d_in[17];
    const float* cls_b2 = (const float*)d_in[18];

    int N = in_sizes[0] / 256;
    int E = in_sizes[1] / 2;
    int L = in_sizes[6] / (3 * HD * HD);
    int Etot = E + N;
    const int* srcA = ei;
    const int* dstA = ei + E;

    float* ws = (float*)d_ws;
    size_t nh = (size_t)N * HD;
    float* h      = ws;
    float* score  = h + nh;
    float* wcomb2 = score + Etot + 64;                          // L * 16384 floats
    unsigned* hbf    = (unsigned*)(wcomb2 + (size_t)L * 16384); // nh/2 uints
    unsigned* paggbf = hbf + nh / 2;                            // nh/2 uints
    unsigned short* w1bf = (unsigned short*)(paggbf + nh / 2);  // L*49152 shorts
    unsigned short* wcbf = w1bf + (size_t)L * 49152;            // L*32768 shorts
    int*   cnt    = (int*)(wcbf + (size_t)L * 32768);
    int*   rowptr = cnt + N;
    int*   cursor = rowptr + N + 1;
    int*   esrc   = cursor + N;
    int*   edst   = esrc + Etot;

    int gemm_blocks = (N + 31) / 32;

    // CSR build (edge_index constant across layers)
    hipMemsetAsync(cnt, 0, (size_t)N * sizeof(int), stream);
    hist_kernel<<<512, 256, 0, stream>>>(dstA, cnt, E, Etot);
    scan_kernel<<<1, 256, 0, stream>>>(cnt, rowptr, cursor, N, Etot);
    scatter_kernel<<<512, 256, 0, stream>>>(srcA, dstA, cursor, esrc, edst, E, Etot);

    // W1 -> bf16 fragment-major (all layers, once)
    int w1_total = L * 49152;
    w1bf_kernel<<<(w1_total + 255) / 256, 256, 0, stream>>>(sim_W1, w1bf, w1_total);

    // wcomb2[l] = W_msg[l] @ W_upd[l][128:256]  (one batched launch)
    wmsg_gemm_kernel<<<4 * L, 256, 0, stream>>>(W_msg, W_upd, wcomb2);
    // wcbf: fragment-major bf16 of [W_upd[l][0:128]; wcomb2[l]]
    int wc_total = L * 32768;
    wcbf_kernel<<<(wc_total + 255) / 256, 256, 0, stream>>>(W_upd, wcomb2, wcbf, wc_total);

    // h = relu(LN(x @ proj_W + b)), hbf mirror
    gemm_rows_kernel<<<gemm_blocks, 256, 0, stream>>>(x, 256, x + 128, 256, proj_W, proj_b,
                                                      nullptr, ln0_g, ln0_b, h, hbf, N);

    int gather_blocks = (N + 3) / 4;          // 5000, divisible by 8
    int upd_blocks = (N + 63) / 64;
    for (int l = 0; l < L; l++) {
        edge_mfma_kernel<<<768, 256, 0, stream>>>(hbf, esrc, edst,
                                                  w1bf + (size_t)l * 49152, sim_b1 + l * HD,
                                                  sim_W2 + l * HD, sim_b2 + l, score, Etot);
        gather_kernel<<<gather_blocks, 256, 0, stream>>>(rowptr, esrc, score, hbf, paggbf, N);
        upd_mfma_kernel<<<upd_blocks, 256, 0, stream>>>(hbf, paggbf, h,
                                                        wcbf + (size_t)l * 32768,
                                                        b_upd + l * HD, ln_g + l * HD, ln_b + l * HD,
                                                        h, hbf, N);
    }
    cls_kernel<<<768, 256, 0, stream>>>(h, cls_W1, cls_b1, cls_W2, cls_b2, (float*)d_out, N);
}